// Round 2
// baseline (4417.876 us; speedup 1.0000x reference)
//
#include <hip/hip_runtime.h>
#include <math.h>

#define DIM    512
#define KCB    8192
#define NROWS  32768

#define BM 128
#define BN 256
#define BK 32
#define TM 8
#define TN 8
#define NTHR 512
#define KSPLIT 2
#define TILES_PER_SPLIT ((KCB / BN) / KSPLIT)   // 16

// ---------------------------------------------------------------------------
// numpy-style pairwise sum of squares over 512 contiguous floats (unchanged
// from the passing round-1 kernel — do not touch, numerics-critical).
// ---------------------------------------------------------------------------
__device__ __forceinline__ float pairwise512_sq(const float* __restrict__ p) {
    float blk[4];
#pragma unroll
    for (int b = 0; b < 4; ++b) {
        const float* a = p + b * 128;
        float r[8];
#pragma unroll
        for (int j = 0; j < 8; ++j) r[j] = __fmul_rn(a[j], a[j]);
#pragma unroll
        for (int i = 8; i < 128; i += 8) {
#pragma unroll
            for (int j = 0; j < 8; ++j)
                r[j] = __fadd_rn(r[j], __fmul_rn(a[i + j], a[i + j]));
        }
        blk[b] = __fadd_rn(__fadd_rn(__fadd_rn(r[0], r[1]), __fadd_rn(r[2], r[3])),
                           __fadd_rn(__fadd_rn(r[4], r[5]), __fadd_rn(r[6], r[7])));
    }
    return __fadd_rn(__fadd_rn(blk[0], blk[1]), __fadd_rn(blk[2], blk[3]));
}

__global__ void ee_kernel(const float* __restrict__ E, float* __restrict__ ee) {
    int k = blockIdx.x * blockDim.x + threadIdx.x;
    if (k < KCB) ee[k] = pairwise512_sq(E + (size_t)k * DIM);
}

// ---------------------------------------------------------------------------
// Fused distance + argmin, round 2:
//  - row-major LDS tiles (stride BK+4=36), ds_write_b128 staging (bank group
//    (r+c)%8 balanced), float4 inner reads with col = tx + 32n (group
//    (tx+kk4)%8, 4 lanes/group = conflict-free minimum)
//  - accumulation order per (row,col) bit-identical to round 1: single fmaf
//    chain, kk ascending
//  - KSPLIT=2 codebook halves per row-block -> 512 blocks = 2/CU; merge via
//    packed (d2_bits<<32|idx) u64 atomicMin == lexicographic (d2, idx) min,
//    valid because d2 ~ 512 > 0.
// ---------------------------------------------------------------------------
__global__ __launch_bounds__(NTHR, 4)
void argmin_kernel(const float* __restrict__ Z, const float* __restrict__ E,
                   const float* __restrict__ ee,
                   unsigned long long* __restrict__ packedOut) {
    __shared__ __align__(16) float As[BM][BK + 4];
    __shared__ __align__(16) float Bs[BN][BK + 4];
    __shared__ float zzs[BM];

    const int tid = threadIdx.x;
    const int tx = tid & 31;
    const int ty = tid >> 5;
    const int rowBase = (blockIdx.x >> 1) * BM;
    const int split = blockIdx.x & 1;

    if (tid < BM) zzs[tid] = pairwise512_sq(Z + (size_t)(rowBase + tid) * DIM);
    __syncthreads();

    float zz[TM];
#pragma unroll
    for (int m = 0; m < TM; ++m) zz[m] = zzs[ty * TM + m];

    float bestV[TM];
    int bestI[TM];
#pragma unroll
    for (int m = 0; m < TM; ++m) { bestV[m] = __builtin_inff(); bestI[m] = 0; }

    for (int t0 = 0; t0 < TILES_PER_SPLIT; ++t0) {
        const int tile = split * TILES_PER_SPLIT + t0;
        float acc[TM][TN];
#pragma unroll
        for (int m = 0; m < TM; ++m)
#pragma unroll
            for (int n = 0; n < TN; ++n) acc[m][n] = 0.0f;

        for (int kc = 0; kc < DIM; kc += BK) {
            __syncthreads();  // previous LDS contents fully consumed
            // stage Z tile (BM x BK) row-major, b128 writes
#pragma unroll
            for (int i = 0; i < (BM * BK / 4) / NTHR; ++i) {  // 2 iters
                int id4 = tid + i * NTHR;
                int r = id4 >> 3, c = id4 & 7;
                float4 v = *(const float4*)(Z + (size_t)(rowBase + r) * DIM + kc + c * 4);
                *(float4*)&As[r][c * 4] = v;
            }
            // stage E tile (BN x BK) row-major, b128 writes
#pragma unroll
            for (int i = 0; i < (BN * BK / 4) / NTHR; ++i) {  // 4 iters
                int id4 = tid + i * NTHR;
                int r = id4 >> 3, c = id4 & 7;
                float4 v = *(const float4*)(E + (size_t)(tile * BN + r) * DIM + kc + c * 4);
                *(float4*)&Bs[r][c * 4] = v;
            }
            __syncthreads();
#pragma unroll
            for (int k4 = 0; k4 < BK / 4; ++k4) {
                float4 a4[TM];
#pragma unroll
                for (int m = 0; m < TM; ++m)
                    a4[m] = *(const float4*)&As[ty * TM + m][k4 * 4];
#pragma unroll
                for (int n = 0; n < TN; ++n) {
                    float4 b4 = *(const float4*)&Bs[tx + 32 * n][k4 * 4];
#pragma unroll
                    for (int m = 0; m < TM; ++m) {
                        float s = acc[m][n];
                        s = __builtin_fmaf(a4[m].x, b4.x, s);
                        s = __builtin_fmaf(a4[m].y, b4.y, s);
                        s = __builtin_fmaf(a4[m].z, b4.z, s);
                        s = __builtin_fmaf(a4[m].w, b4.w, s);
                        acc[m][n] = s;
                    }
                }
            }
        }

        // argmin update: for fixed m, n ascending => kidx ascending (strict <
        // keeps the first/lowest index, matching numpy tie-break)
#pragma unroll
        for (int n = 0; n < TN; ++n) {
            const int kidx = tile * BN + tx + 32 * n;
            const float eevn = ee[kidx];
#pragma unroll
            for (int m = 0; m < TM; ++m) {
                float t = __builtin_fmaf(-2.0f, acc[m][n], zz[m]); // fl(zz - 2*dot)
                float d2 = __fadd_rn(t, eevn);                     // fl(t + ee)
                if (d2 < bestV[m]) { bestV[m] = d2; bestI[m] = kidx; }
            }
        }
    }

    // cross-thread (tx) argmin reduction, overlaying the staging LDS
    __syncthreads();
    float (*redV)[33] = (float (*)[33])&As[0][0];   // 128*33 <= 128*36 floats
    int   (*redI)[33] = (int (*)[33])&Bs[0][0];     // 128*33 <= 256*36 ints
#pragma unroll
    for (int m = 0; m < TM; ++m) {
        redV[ty * TM + m][tx] = bestV[m];
        redI[ty * TM + m][tx] = bestI[m];
    }
    __syncthreads();
    if (tid < BM) {
        float bv = redV[tid][0];
        int bi = redI[tid][0];
        for (int j = 1; j < 32; ++j) {
            float v = redV[tid][j];
            int ii = redI[tid][j];
            if (v < bv || (v == bv && ii < bi)) { bv = v; bi = ii; }
        }
        unsigned long long pk =
            ((unsigned long long)__float_as_uint(bv) << 32) | (unsigned int)bi;
        atomicMin(&packedOut[rowBase + tid], pk);
    }
}

// ---------------------------------------------------------------------------
// Gather z_q, write z_q_st (exact rounding mimic), indices as float, f64 loss.
// ---------------------------------------------------------------------------
__global__ void gather_kernel(const float* __restrict__ Z, const float* __restrict__ E,
                              const unsigned long long* __restrict__ packed,
                              float* __restrict__ outZ,
                              float* __restrict__ outIdxF, double* __restrict__ lossAcc) {
    int row = blockIdx.x;
    int t = threadIdx.x;  // 64 threads
    int k = (int)(packed[row] & 0xFFFFFFFFull);
    const float* zr = Z + (size_t)row * DIM;
    const float* er = E + (size_t)k * DIM;
    float* orow = outZ + (size_t)row * DIM;
    double s = 0.0;
#pragma unroll
    for (int i = 0; i < 2; ++i) {
        int off = (t + i * 64) * 4;
        float4 z4 = *(const float4*)(zr + off);
        float4 e4 = *(const float4*)(er + off);
        float dx = __fsub_rn(e4.x, z4.x);
        float dy = __fsub_rn(e4.y, z4.y);
        float dz = __fsub_rn(e4.z, z4.z);
        float dw = __fsub_rn(e4.w, z4.w);
        float4 st;
        st.x = __fadd_rn(z4.x, dx);
        st.y = __fadd_rn(z4.y, dy);
        st.z = __fadd_rn(z4.z, dz);
        st.w = __fadd_rn(z4.w, dw);
        *(float4*)(orow + off) = st;
        s += (double)dx * dx + (double)dy * dy + (double)dz * dz + (double)dw * dw;
    }
#pragma unroll
    for (int o = 32; o > 0; o >>= 1) s += __shfl_down(s, o, 64);
    if (t == 0) {
        atomicAdd(lossAcc, s);
        outIdxF[row] = (float)k;
    }
}

__global__ void finalize_kernel(const double* __restrict__ lossAcc,
                                float* __restrict__ outLoss) {
    double m = *lossAcc / (double)((size_t)NROWS * DIM);
    float mf = (float)m;
    float c = __fmul_rn(0.25f, mf);   // commitment = BETA * mean
    *outLoss = __fadd_rn(c, mf);      // vq_loss = commitment + embedding
}

// ---------------------------------------------------------------------------
// ws layout (bytes):
//   [0,      32768)  float ee[8192]
//   [32768, 294912)  u64 packed[32768]  (init 0xFF per call)
//   [294912,294920)  double loss accumulator
// ---------------------------------------------------------------------------
extern "C" void kernel_launch(void* const* d_in, const int* in_sizes, int n_in,
                              void* d_out, int out_size, void* d_ws, size_t ws_size,
                              hipStream_t stream) {
    const float* Z = (const float*)d_in[0];   // z_e: 8*4096*512
    const float* E = (const float*)d_in[1];   // embeddings: 8192*512
    float* out = (float*)d_out;
    float* zq_out = out;                               // [0, 16777216)
    float* loss_out = out + (size_t)NROWS * DIM;       // [16777216]
    float* idxf_out = loss_out + 1;                    // [16777217, +32768)

    float* ee = (float*)d_ws;
    unsigned long long* packed = (unsigned long long*)((char*)d_ws + 32768);
    double* lossAcc = (double*)((char*)d_ws + 294912);

    hipMemsetAsync(packed, 0xFF, NROWS * sizeof(unsigned long long), stream);
    hipMemsetAsync(lossAcc, 0, sizeof(double), stream);
    ee_kernel<<<KCB / 256, 256, 0, stream>>>(E, ee);
    argmin_kernel<<<NROWS / BM * KSPLIT, NTHR, 0, stream>>>(Z, E, ee, packed);
    gather_kernel<<<NROWS, 64, 0, stream>>>(Z, E, packed, zq_out, idxf_out, lossAcc);
    finalize_kernel<<<1, 1, 0, stream>>>(lossAcc, loss_out);
}

// Round 3
// 1248.415 us; speedup vs baseline: 3.5388x; 3.5388x over previous
//
#include <hip/hip_runtime.h>
#include <math.h>

#define DIM    512
#define KCB    8192
#define NROWS  32768

typedef _Float16 f16x8 __attribute__((ext_vector_type(8)));
typedef float    f32x4 __attribute__((ext_vector_type(4)));

// ---- workspace layout (main path) ----
#define OFF_ZH    0ull                    // f16 Z  [32768][512] = 33554432 B
#define OFF_EH    33554432ull             // f16 E  [8192][512]  =  8388608 B
#define OFF_EE    41943040ull             // f32 ee [8192]
#define OFF_ZZ    41975808ull             // f32 zz [32768]
#define OFF_CNT   42106880ull             // u32 cnt[32768]
#define OFF_CAND  42237952ull             // u32 cand[32768][64]
#define OFF_IDX   50626560ull             // i32 idx[32768]
#define OFF_LOSS  50757632ull             // f64 loss accumulator
#define WS_NEEDED 50757640ull
#define CAP 64
#define MARGIN 5.0e-4f

// ---------------------------------------------------------------------------
// numpy-pairwise sum of squares, 512 floats. Identical arithmetic to the
// round-1 passing version; loads vectorized (float4) — loads don't round.
// ---------------------------------------------------------------------------
__device__ __forceinline__ float pairwise512_sq_v(const float* __restrict__ p) {
    float blk[4];
#pragma unroll
    for (int b = 0; b < 4; ++b) {
        const float4* a4 = (const float4*)(p + b * 128);
        float4 v0 = a4[0], v1 = a4[1];
        float r[8];
        r[0] = __fmul_rn(v0.x, v0.x); r[1] = __fmul_rn(v0.y, v0.y);
        r[2] = __fmul_rn(v0.z, v0.z); r[3] = __fmul_rn(v0.w, v0.w);
        r[4] = __fmul_rn(v1.x, v1.x); r[5] = __fmul_rn(v1.y, v1.y);
        r[6] = __fmul_rn(v1.z, v1.z); r[7] = __fmul_rn(v1.w, v1.w);
#pragma unroll
        for (int i = 1; i < 16; ++i) {
            v0 = a4[i * 2]; v1 = a4[i * 2 + 1];
            r[0] = __fadd_rn(r[0], __fmul_rn(v0.x, v0.x));
            r[1] = __fadd_rn(r[1], __fmul_rn(v0.y, v0.y));
            r[2] = __fadd_rn(r[2], __fmul_rn(v0.z, v0.z));
            r[3] = __fadd_rn(r[3], __fmul_rn(v0.w, v0.w));
            r[4] = __fadd_rn(r[4], __fmul_rn(v1.x, v1.x));
            r[5] = __fadd_rn(r[5], __fmul_rn(v1.y, v1.y));
            r[6] = __fadd_rn(r[6], __fmul_rn(v1.z, v1.z));
            r[7] = __fadd_rn(r[7], __fmul_rn(v1.w, v1.w));
        }
        blk[b] = __fadd_rn(__fadd_rn(__fadd_rn(r[0], r[1]), __fadd_rn(r[2], r[3])),
                           __fadd_rn(__fadd_rn(r[4], r[5]), __fadd_rn(r[6], r[7])));
    }
    return __fadd_rn(__fadd_rn(blk[0], blk[1]), __fadd_rn(blk[2], blk[3]));
}

__global__ void ee_kernel(const float* __restrict__ E, float* __restrict__ ee) {
    int k = blockIdx.x * blockDim.x + threadIdx.x;
    if (k < KCB) ee[k] = pairwise512_sq_v(E + (size_t)k * DIM);
}

__global__ void zz_kernel(const float* __restrict__ Z, float* __restrict__ zz) {
    int r = blockIdx.x * blockDim.x + threadIdx.x;
    if (r < NROWS) zz[r] = pairwise512_sq_v(Z + (size_t)r * DIM);
}

// f32 -> f16 (RNE), 8 elems/thread
__global__ void cvt_kernel(const float* __restrict__ in, _Float16* __restrict__ out, int n8) {
    int i = blockIdx.x * blockDim.x + threadIdx.x;
    if (i >= n8) return;
    const float4* p = (const float4*)in + (size_t)i * 2;
    float4 v0 = p[0], v1 = p[1];
    f16x8 h;
    h[0] = (_Float16)v0.x; h[1] = (_Float16)v0.y; h[2] = (_Float16)v0.z; h[3] = (_Float16)v0.w;
    h[4] = (_Float16)v1.x; h[5] = (_Float16)v1.y; h[6] = (_Float16)v1.z; h[7] = (_Float16)v1.w;
    *(f16x8*)(out + (size_t)i * 8) = h;
}

// ---------------------------------------------------------------------------
// MFMA screen: per 128-row block, sweep all 8192 codes in 256-code tiles,
// K=512 fully accumulated per tile (8 ksteps x BK=64, mfma 16x16x32 f16).
// A-panel [128][512] f16 resident in LDS (XOR-swizzled, staged once);
// B-tile [256][64] f16 restaged per kstep. 8 waves = 2(row) x 4(col),
// wave tile 64x64 = 4x4 fragments. Epilogue: crit = ee[k] - 2*dot;
// wave-local per-row running min; append candidates with crit <= min+MARGIN.
// ---------------------------------------------------------------------------
__global__ __launch_bounds__(512, 2)
void screen_kernel(const _Float16* __restrict__ Zh, const _Float16* __restrict__ Eh,
                   const float* __restrict__ ee,
                   unsigned int* __restrict__ cnt, unsigned int* __restrict__ cand) {
    __shared__ __align__(16) char lds[128 * 512 * 2 + 256 * 64 * 2];  // 160 KiB
    char* Ab = lds;                   // swizzled [128][512] f16 (1 KiB rows)
    char* Bb = lds + 128 * 512 * 2;   // swizzled [256][64] f16 (128 B rows)

    const int tid = threadIdx.x;
    const int l = tid & 63;
    const int w = tid >> 6;
    const int wrow = w >> 2;          // 0..1
    const int wcol = w & 3;           // 0..3
    const int rowBase = blockIdx.x * 128;

    // stage A once: 8192 16B-chunks; swizzle slot s -> s^(r&7) via source index
#pragma unroll
    for (int i = 0; i < 16; ++i) {
        int id = tid + i * 512;
        int r = id >> 6, t = id & 63;
        int s = t ^ (r & 7);
        f16x8 v = *(const f16x8*)(Zh + (size_t)(rowBase + r) * DIM + s * 8);
        *(f16x8*)(Ab + r * 1024 + t * 16) = v;
    }

    float runmin[16];
#pragma unroll
    for (int q = 0; q < 16; ++q) runmin[q] = __builtin_inff();

    for (int tile = 0; tile < 32; ++tile) {
        f32x4 acc[4][4];
#pragma unroll
        for (int m = 0; m < 4; ++m)
#pragma unroll
            for (int n = 0; n < 4; ++n) acc[m][n] = (f32x4){0.f, 0.f, 0.f, 0.f};

        for (int ks = 0; ks < 8; ++ks) {
            __syncthreads();
            // stage B tile-slice: 2048 16B-chunks, 4/thread
#pragma unroll
            for (int i = 0; i < 4; ++i) {
                int id = w * 256 + i * 64 + l;
                int c = id >> 3, t = id & 7;
                int s = t ^ (c & 7);
                f16x8 v = *(const f16x8*)(Eh + (size_t)(tile * 256 + c) * DIM + ks * 64 + s * 8);
                *(f16x8*)(Bb + c * 128 + t * 16) = v;
            }
            __syncthreads();
            f16x8 af[4][2], bf[4][2];
#pragma unroll
            for (int m = 0; m < 4; ++m)
#pragma unroll
                for (int k2 = 0; k2 < 2; ++k2) {
                    int row = wrow * 64 + m * 16 + (l & 15);
                    int s = ks * 8 + k2 * 4 + (l >> 4);
                    af[m][k2] = *(const f16x8*)(Ab + row * 1024 + (s ^ (row & 7)) * 16);
                }
#pragma unroll
            for (int n = 0; n < 4; ++n)
#pragma unroll
                for (int k2 = 0; k2 < 2; ++k2) {
                    int c = wcol * 64 + n * 16 + (l & 15);
                    int s = k2 * 4 + (l >> 4);
                    bf[n][k2] = *(const f16x8*)(Bb + c * 128 + (s ^ (c & 7)) * 16);
                }
#pragma unroll
            for (int m = 0; m < 4; ++m)
#pragma unroll
                for (int n = 0; n < 4; ++n) {
                    acc[m][n] = __builtin_amdgcn_mfma_f32_16x16x32_f16(af[m][0], bf[n][0], acc[m][n], 0, 0, 0);
                    acc[m][n] = __builtin_amdgcn_mfma_f32_16x16x32_f16(af[m][1], bf[n][1], acc[m][n], 0, 0, 0);
                }
        }

        // epilogue: crit, running min, candidate append
        float eev[4];
#pragma unroll
        for (int n = 0; n < 4; ++n)
            eev[n] = ee[tile * 256 + wcol * 64 + n * 16 + (l & 15)];
#pragma unroll
        for (int m = 0; m < 4; ++m) {
#pragma unroll
            for (int r = 0; r < 4; ++r) {
                float cr[4];
#pragma unroll
                for (int n = 0; n < 4; ++n) cr[n] = fmaf(-2.0f, acc[m][n][r], eev[n]);
                float mn = fminf(fminf(cr[0], cr[1]), fminf(cr[2], cr[3]));
#pragma unroll
                for (int off = 1; off < 16; off <<= 1)
                    mn = fminf(mn, __shfl_xor(mn, off, 64));
                const int q = m * 4 + r;
                float rm = fminf(runmin[q], mn);
                runmin[q] = rm;
                float thr = rm + MARGIN;
                int rowg = rowBase + wrow * 64 + m * 16 + (l >> 4) * 4 + r;
#pragma unroll
                for (int n = 0; n < 4; ++n) {
                    if (cr[n] <= thr) {
                        unsigned pos = atomicAdd(&cnt[rowg], 1u);
                        if (pos < CAP)
                            cand[(size_t)rowg * CAP + pos] =
                                (unsigned)(tile * 256 + wcol * 64 + n * 16 + (l & 15));
                    }
                }
            }
        }
    }
}

// ---------------------------------------------------------------------------
// Exact rescore: one wave per row, one candidate per lane. d2 computed with
// the bit-identical round-1 chain (sequential fmaf ascending k;
// fmaf(-2,dot,zz); +ee). Lex-(d2,idx) min -> winner.
// ---------------------------------------------------------------------------
__global__ void rescore_kernel(const float* __restrict__ Z, const float* __restrict__ E,
                               const float* __restrict__ zz, const float* __restrict__ ee,
                               const unsigned int* __restrict__ cnt,
                               const unsigned int* __restrict__ cand,
                               int* __restrict__ idx) {
    int row = blockIdx.x;
    int l = threadIdx.x;  // 64
    unsigned c = cnt[row]; if (c > CAP) c = CAP;
    float d2 = __builtin_inff();
    int kk = 0x7FFFFFFF;
    if (l < (int)c) {
        int k = (int)cand[(size_t)row * CAP + l];
        const float* zr = Z + (size_t)row * DIM;
        const float* er = E + (size_t)k * DIM;
        float s = 0.0f;
        for (int i = 0; i < DIM; ++i) s = __builtin_fmaf(zr[i], er[i], s);
        float t = __builtin_fmaf(-2.0f, s, zz[row]);
        d2 = __fadd_rn(t, ee[k]);
        kk = k;
    }
#pragma unroll
    for (int off = 32; off > 0; off >>= 1) {
        float od = __shfl_down(d2, off, 64);
        int ok = __shfl_down(kk, off, 64);
        if (od < d2 || (od == d2 && ok < kk)) { d2 = od; kk = ok; }
    }
    if (l == 0) idx[row] = kk;
}

// ---------------------------------------------------------------------------
// Gather + straight-through output + f64 loss (unchanged from round 1).
// ---------------------------------------------------------------------------
__global__ void gather_kernel(const float* __restrict__ Z, const float* __restrict__ E,
                              const int* __restrict__ idx, float* __restrict__ outZ,
                              float* __restrict__ outIdxF, double* __restrict__ lossAcc) {
    int row = blockIdx.x;
    int t = threadIdx.x;  // 64
    int k = idx[row];
    const float* zr = Z + (size_t)row * DIM;
    const float* er = E + (size_t)k * DIM;
    float* orow = outZ + (size_t)row * DIM;
    double s = 0.0;
#pragma unroll
    for (int i = 0; i < 2; ++i) {
        int off = (t + i * 64) * 4;
        float4 z4 = *(const float4*)(zr + off);
        float4 e4 = *(const float4*)(er + off);
        float dx = __fsub_rn(e4.x, z4.x);
        float dy = __fsub_rn(e4.y, z4.y);
        float dz = __fsub_rn(e4.z, z4.z);
        float dw = __fsub_rn(e4.w, z4.w);
        float4 st;
        st.x = __fadd_rn(z4.x, dx);
        st.y = __fadd_rn(z4.y, dy);
        st.z = __fadd_rn(z4.z, dz);
        st.w = __fadd_rn(z4.w, dw);
        *(float4*)(orow + off) = st;
        s += (double)dx * dx + (double)dy * dy + (double)dz * dz + (double)dw * dw;
    }
#pragma unroll
    for (int o = 32; o > 0; o >>= 1) s += __shfl_down(s, o, 64);
    if (t == 0) {
        atomicAdd(lossAcc, s);
        outIdxF[row] = (float)k;
    }
}

__global__ void finalize_kernel(const double* __restrict__ lossAcc,
                                float* __restrict__ outLoss) {
    double m = *lossAcc / (double)((size_t)NROWS * DIM);
    float mf = (float)m;
    float c = __fmul_rn(0.25f, mf);
    *outLoss = __fadd_rn(c, mf);
}

// ---------------------------------------------------------------------------
// Fallback (ws too small): round-1 proven-correct VALU argmin, verbatim.
// ---------------------------------------------------------------------------
__device__ __forceinline__ float pairwise512_sq(const float* __restrict__ p) {
    float blk[4];
#pragma unroll
    for (int b = 0; b < 4; ++b) {
        const float* a = p + b * 128;
        float r[8];
#pragma unroll
        for (int j = 0; j < 8; ++j) r[j] = __fmul_rn(a[j], a[j]);
#pragma unroll
        for (int i = 8; i < 128; i += 8) {
#pragma unroll
            for (int j = 0; j < 8; ++j)
                r[j] = __fadd_rn(r[j], __fmul_rn(a[i + j], a[i + j]));
        }
        blk[b] = __fadd_rn(__fadd_rn(__fadd_rn(r[0], r[1]), __fadd_rn(r[2], r[3])),
                           __fadd_rn(__fadd_rn(r[4], r[5]), __fadd_rn(r[6], r[7])));
    }
    return __fadd_rn(__fadd_rn(blk[0], blk[1]), __fadd_rn(blk[2], blk[3]));
}

__global__ __launch_bounds__(512, 2)
void argmin_fallback(const float* __restrict__ Z, const float* __restrict__ E,
                     const float* __restrict__ ee, int* __restrict__ outIdx) {
    __shared__ __align__(16) char smem[(32 * 132 + 32 * 260) * 4];
    float (*As)[132] = (float (*)[132])smem;
    float (*Bs)[260] = (float (*)[260])(smem + 32 * 132 * 4);
    __shared__ float zzs[128];
    const int tid = threadIdx.x;
    const int tx = tid & 31;
    const int ty = tid >> 5;
    const int rowBase = blockIdx.x * 128;
    if (tid < 128) zzs[tid] = pairwise512_sq(Z + (size_t)(rowBase + tid) * DIM);
    __syncthreads();
    float zz[8];
#pragma unroll
    for (int m = 0; m < 8; ++m) zz[m] = zzs[ty * 8 + m];
    float bestV[8]; int bestI[8];
#pragma unroll
    for (int m = 0; m < 8; ++m) { bestV[m] = __builtin_inff(); bestI[m] = 0; }
    for (int tile = 0; tile < 32; ++tile) {
        float acc[8][8];
#pragma unroll
        for (int m = 0; m < 8; ++m)
#pragma unroll
            for (int n = 0; n < 8; ++n) acc[m][n] = 0.0f;
        for (int kc = 0; kc < DIM; kc += 32) {
            __syncthreads();
#pragma unroll
            for (int i = 0; i < 2; ++i) {
                int id4 = tid + i * 512;
                int r = id4 >> 3, c = id4 & 7;
                float4 v = *(const float4*)(Z + (size_t)(rowBase + r) * DIM + kc + c * 4);
                As[c * 4 + 0][r] = v.x; As[c * 4 + 1][r] = v.y;
                As[c * 4 + 2][r] = v.z; As[c * 4 + 3][r] = v.w;
            }
#pragma unroll
            for (int i = 0; i < 4; ++i) {
                int id4 = tid + i * 512;
                int r = id4 >> 3, c = id4 & 7;
                float4 v = *(const float4*)(E + (size_t)(tile * 256 + r) * DIM + kc + c * 4);
                Bs[c * 4 + 0][r] = v.x; Bs[c * 4 + 1][r] = v.y;
                Bs[c * 4 + 2][r] = v.z; Bs[c * 4 + 3][r] = v.w;
            }
            __syncthreads();
#pragma unroll
            for (int kk = 0; kk < 32; ++kk) {
                float a[8], b[8];
                *(float4*)&a[0] = *(const float4*)&As[kk][ty * 8];
                *(float4*)&a[4] = *(const float4*)&As[kk][ty * 8 + 4];
                *(float4*)&b[0] = *(const float4*)&Bs[kk][tx * 8];
                *(float4*)&b[4] = *(const float4*)&Bs[kk][tx * 8 + 4];
#pragma unroll
                for (int m = 0; m < 8; ++m)
#pragma unroll
                    for (int n = 0; n < 8; ++n)
                        acc[m][n] = __builtin_fmaf(a[m], b[n], acc[m][n]);
            }
        }
#pragma unroll
        for (int m = 0; m < 8; ++m) {
#pragma unroll
            for (int n = 0; n < 8; ++n) {
                float t = __builtin_fmaf(-2.0f, acc[m][n], zz[m]);
                float d2 = __fadd_rn(t, ee[tile * 256 + tx * 8 + n]);
                int kidx = tile * 256 + tx * 8 + n;
                if (d2 < bestV[m]) { bestV[m] = d2; bestI[m] = kidx; }
            }
        }
    }
    __syncthreads();
    float (*redV)[33] = (float (*)[33])smem;
    int   (*redI)[33] = (int (*)[33])(smem + 128 * 33 * 4);
#pragma unroll
    for (int m = 0; m < 8; ++m) {
        redV[ty * 8 + m][tx] = bestV[m];
        redI[ty * 8 + m][tx] = bestI[m];
    }
    __syncthreads();
    if (tid < 128) {
        float bv = redV[tid][0]; int bi = redI[tid][0];
        for (int j = 1; j < 32; ++j) {
            float v = redV[tid][j]; int ii = redI[tid][j];
            if (v < bv || (v == bv && ii < bi)) { bv = v; bi = ii; }
        }
        outIdx[rowBase + tid] = bi;
    }
}

// ---------------------------------------------------------------------------
extern "C" void kernel_launch(void* const* d_in, const int* in_sizes, int n_in,
                              void* d_out, int out_size, void* d_ws, size_t ws_size,
                              hipStream_t stream) {
    const float* Z = (const float*)d_in[0];
    const float* E = (const float*)d_in[1];
    float* out = (float*)d_out;
    float* zq_out = out;
    float* loss_out = out + (size_t)NROWS * DIM;
    float* idxf_out = loss_out + 1;

    if (ws_size >= WS_NEEDED) {
        _Float16* Zh = (_Float16*)((char*)d_ws + OFF_ZH);
        _Float16* Eh = (_Float16*)((char*)d_ws + OFF_EH);
        float* ee = (float*)((char*)d_ws + OFF_EE);
        float* zz = (float*)((char*)d_ws + OFF_ZZ);
        unsigned int* cnt = (unsigned int*)((char*)d_ws + OFF_CNT);
        unsigned int* cand = (unsigned int*)((char*)d_ws + OFF_CAND);
        int* idx = (int*)((char*)d_ws + OFF_IDX);
        double* lossAcc = (double*)((char*)d_ws + OFF_LOSS);

        hipMemsetAsync(cnt, 0, NROWS * sizeof(unsigned int), stream);
        hipMemsetAsync(lossAcc, 0, sizeof(double), stream);
        cvt_kernel<<<(NROWS * DIM / 8 + 255) / 256, 256, 0, stream>>>(Z, Zh, NROWS * DIM / 8);
        cvt_kernel<<<(KCB * DIM / 8 + 255) / 256, 256, 0, stream>>>(E, Eh, KCB * DIM / 8);
        ee_kernel<<<KCB / 256, 256, 0, stream>>>(E, ee);
        zz_kernel<<<NROWS / 256, 256, 0, stream>>>(Z, zz);
        screen_kernel<<<NROWS / 128, 512, 0, stream>>>(Zh, Eh, ee, cnt, cand);
        rescore_kernel<<<NROWS, 64, 0, stream>>>(Z, E, zz, ee, cnt, cand, idx);
        gather_kernel<<<NROWS, 64, 0, stream>>>(Z, E, idx, zq_out, idxf_out, lossAcc);
        finalize_kernel<<<1, 1, 0, stream>>>(lossAcc, loss_out);
    } else {
        float* ee = (float*)d_ws;
        int* idx = (int*)((char*)d_ws + 32768);
        double* lossAcc = (double*)((char*)d_ws + 163840);
        hipMemsetAsync(lossAcc, 0, sizeof(double), stream);
        ee_kernel<<<KCB / 256, 256, 0, stream>>>(E, ee);
        argmin_fallback<<<NROWS / 128, 512, 0, stream>>>(Z, E, ee, idx);
        gather_kernel<<<NROWS, 64, 0, stream>>>(Z, E, idx, zq_out, idxf_out, lossAcc);
        finalize_kernel<<<1, 1, 0, stream>>>(lossAcc, loss_out);
    }
}